// Round 7
// baseline (161.920 us; speedup 1.0000x reference)
//
#include <hip/hip_runtime.h>
#include <stdint.h>

#define BATCH 2
#define NH 16
#define SEQ 2048
#define DIM 1024
#define HD 64
#define MROWS (BATCH*SEQ)   // 4096

typedef __attribute__((ext_vector_type(8))) _Float16 f16x8;
typedef __attribute__((ext_vector_type(16))) float f32x16;
typedef __attribute__((ext_vector_type(4))) float f32x4;
typedef __attribute__((ext_vector_type(2))) __fp16 fp16x2;
typedef __attribute__((ext_vector_type(4))) short short4v;

__device__ __forceinline__ short f2h(float f) {
  union { _Float16 h; short s; } u;
  u.h = (_Float16)f;
  return u.s;
}

__device__ __forceinline__ float fast_exp2(float x) {
#if __has_builtin(__builtin_amdgcn_exp2f)
  return __builtin_amdgcn_exp2f(x);
#else
  return exp2f(x);
#endif
}

__device__ __forceinline__ unsigned pk2(float a, float b) {
  union { fp16x2 h; unsigned u; } x;
  x.h = __builtin_amdgcn_cvt_pkrtz(a, b);
  return x.u;
}

// a.hi(lanes32-63) <-> b.lo(lanes0-31), via known-good shuffle primitives.
__device__ __forceinline__ void perm32swap(unsigned &a, unsigned &b) {
  unsigned as = (unsigned)__shfl_xor((int)a, 32);
  unsigned bs = (unsigned)__shfl_xor((int)b, 32);
  bool lo = ((threadIdx.x & 63) < 32);
  unsigned na = lo ? a : bs;   // hi lanes receive b.lo
  unsigned nb = lo ? as : b;   // lo lanes receive a.hi
  a = na; b = nb;
}

__device__ __forceinline__ void async_load16(const void* g, void* l) {
  __builtin_amdgcn_global_load_lds((const __attribute__((address_space(1))) void*)g,
                                   (__attribute__((address_space(3))) void*)l, 16, 0, 0);
}

// ---------------- convert f32 -> f16 ----------------
__global__ __launch_bounds__(256) void k_cvt(const float* __restrict__ in,
                                             short* __restrict__ out, int n4) {
  int i = blockIdx.x * 256 + threadIdx.x;
  if (i >= n4) return;
  float4 v = ((const float4*)in)[i];
  short4v o;
  o[0] = f2h(v.x); o[1] = f2h(v.y); o[2] = f2h(v.z); o[3] = f2h(v.w);
  ((short4v*)out)[i] = o;
}

// ---------------- transpose (K x N) f32 -> (N x K) f16 ----------------
__global__ __launch_bounds__(256) void k_transpose(const float* __restrict__ in,
                                                   short* __restrict__ out,
                                                   int K, int N) {
  __shared__ float t[32][33];
  int n0 = blockIdx.x * 32, k0 = blockIdx.y * 32;
  int tx = threadIdx.x, ty = threadIdx.y;  // 32 x 8
  #pragma unroll
  for (int i = 0; i < 32; i += 8)
    t[ty + i][tx] = in[(size_t)(k0 + ty + i) * N + (n0 + tx)];
  __syncthreads();
  #pragma unroll
  for (int i = 0; i < 32; i += 8)
    out[(size_t)(n0 + ty + i) * K + (k0 + tx)] = f2h(t[tx][ty + i]);
}

// ---------------- GEMM  C[M,N] = A[M,K] * Bt[N,K]^T  (fp16 in, f32 acc) ---
// MODE 0: QKV epilogue -> Q (n-major, scaled by scale*log2e),
//         K,V in MFMA-fragment-major layouts for k_flash (see k_flash docs)
// MODE 1: f32 output + bias
template <int MODE>
__global__ __launch_bounds__(256) void k_gemm_bt(
    const short* __restrict__ A, const short* __restrict__ Bt,
    const float* __restrict__ bias,
    short* __restrict__ Qd, short* __restrict__ Kd, short* __restrict__ Vtd,
    float* __restrict__ Cf, int Ncols, int Kdim) {
  constexpr int BM = 128, BN = 128, BK = 32;
  __shared__ short Al[BM * BK];
  __shared__ short Bl[BN * BK];
  const int tid = threadIdx.x;
  const int lane = tid & 63;
  const int wid = tid >> 6;
  const int wr = wid >> 1, wc = wid & 1;
  const int m0 = blockIdx.y * BM, n0 = blockIdx.x * BN;
  const int l15 = lane & 15, lk = (lane >> 4) * 8;

  f32x4 acc[4][4] = {};

  for (int k0 = 0; k0 < Kdim; k0 += BK) {
    __syncthreads();
    #pragma unroll
    for (int i = 0; i < 2; i++) {
      int c = i * 256 + tid;                 // 512 chunks of 16B = 8KB tile
      async_load16(A + (size_t)(m0 + (c >> 2)) * Kdim + k0 + (c & 3) * 8, &Al[c * 8]);
    }
    #pragma unroll
    for (int i = 0; i < 2; i++) {
      int c = i * 256 + tid;
      async_load16(Bt + (size_t)(n0 + (c >> 2)) * Kdim + k0 + (c & 3) * 8, &Bl[c * 8]);
    }
    __syncthreads();  // compiler emits vmcnt(0) drain before barrier

    f16x8 af[4], bfr[4];
    #pragma unroll
    for (int i = 0; i < 4; i++)
      af[i] = *(const f16x8*)&Al[(wr * 64 + i * 16 + l15) * BK + lk];
    #pragma unroll
    for (int j = 0; j < 4; j++)
      bfr[j] = *(const f16x8*)&Bl[(wc * 64 + j * 16 + l15) * BK + lk];
    #pragma unroll
    for (int i = 0; i < 4; i++)
      #pragma unroll
      for (int j = 0; j < 4; j++)
        acc[i][j] = __builtin_amdgcn_mfma_f32_16x16x32_f16(af[i], bfr[j], acc[i][j], 0, 0, 0);
  }

  const int rl = (lane >> 4) * 4;
  if (MODE == 0) {
    #pragma unroll
    for (int j = 0; j < 4; j++) {
      int col = n0 + wc * 64 + j * 16 + l15;
      float bv = bias[col];
      int sec = col >> 10;          // 0=Q 1=K 2=V
      int cc = col & 1023;
      int h = cc >> 6, hd = cc & 63;
      // fold softmax scale AND log2(e) into Q so attention uses raw exp2
      float mul = (sec == 0) ? (0.125f * 1.44269504088896f) : 1.0f;
      #pragma unroll
      for (int i = 0; i < 4; i++) {
        int rowb = m0 + wr * 64 + i * 16 + rl;
        #pragma unroll
        for (int r = 0; r < 4; r++) {
          int row = rowb + r;
          int b = row >> 11, nr = row & 2047;
          short v = f2h((acc[i][j][r] + bv) * mul);
          size_t bh = (size_t)(b * NH + h);
          size_t base2 = bh * (size_t)(SEQ * HD);
          if (sec == 0) {
            Qd[base2 + (size_t)nr * HD + hd] = v;
          } else if (sec == 1) {
            // K A-frag layout: [(nr>>5)*4 + hd>>4][lane=((hd>>3)&1)*32+(nr&31)][i=hd&7]
            Kd[base2 + (size_t)(((nr >> 5) * 4 + (hd >> 4)) * 512 +
                                (((hd >> 3) & 1) * 32 + (nr & 31)) * 8 + (hd & 7))] = v;
          } else {
            // V B-frag layout: [(nr>>4)*2 + hd>>5][lane=((nr>>3)&1)*32+(hd&31)][i=nr&7]
            Vtd[base2 + (size_t)(((nr >> 4) * 2 + (hd >> 5)) * 512 +
                                 (((nr >> 3) & 1) * 32 + (hd & 31)) * 8 + (nr & 7))] = v;
          }
        }
      }
    }
  } else {
    #pragma unroll
    for (int j = 0; j < 4; j++) {
      int col = n0 + wc * 64 + j * 16 + l15;
      float bv = bias[col];
      #pragma unroll
      for (int i = 0; i < 4; i++) {
        int rowb = m0 + wr * 64 + i * 16 + rl;
        #pragma unroll
        for (int r = 0; r < 4; r++)
          Cf[(size_t)(rowb + r) * Ncols + col] = acc[i][j][r] + bv;
      }
    }
  }
}

// ---------------- flash attention v3 ----------------
// 32x32x16 MFMA, static softmax (log2e folded into Q), P entirely in
// registers via cvt_pkrtz + cross-half swap (shuffle-based). K/V staged
// with linear global_load_lds from fragment-major global layouts; all LDS
// reads lane-linear ds_read_b128. Wave owns 64 q-rows; block = 4 waves.
#define QBLK 256
#define NKVT (SEQ / 64)

// exp2 + pack 8 score regs (R0..R0+7) of one 32x32 C-tile into one PV
// A-fragment (f16x8) for its 16-kv slice.
#define PACK8(sv, R0, lsv, OUT) do {                                        \
    float e0_ = fast_exp2((sv)[R0 + 0]), e1_ = fast_exp2((sv)[R0 + 1]);     \
    float e2_ = fast_exp2((sv)[R0 + 2]), e3_ = fast_exp2((sv)[R0 + 3]);     \
    float e4_ = fast_exp2((sv)[R0 + 4]), e5_ = fast_exp2((sv)[R0 + 5]);     \
    float e6_ = fast_exp2((sv)[R0 + 6]), e7_ = fast_exp2((sv)[R0 + 7]);     \
    lsv += ((e0_ + e1_) + (e2_ + e3_)) + ((e4_ + e5_) + (e6_ + e7_));       \
    unsigned u0_ = pk2(e0_, e1_), u1_ = pk2(e2_, e3_);                      \
    unsigned u2_ = pk2(e4_, e5_), u3_ = pk2(e6_, e7_);                      \
    perm32swap(u0_, u2_);                                                   \
    perm32swap(u1_, u3_);                                                   \
    union { unsigned u[4]; f16x8 v; } W_;                                   \
    W_.u[0] = u0_; W_.u[1] = u1_; W_.u[2] = u2_; W_.u[3] = u3_;             \
    OUT = W_.v;                                                             \
  } while (0)

__global__ __launch_bounds__(256) void k_flash(const short* __restrict__ Qd,
                                               const short* __restrict__ KB,
                                               const short* __restrict__ VB,
                                               short* __restrict__ Od) {
  __shared__ short Kl[2][4096];
  __shared__ short Vl[2][4096];
  const int tid = threadIdx.x;
  const int lane = tid & 63;
  const int w = tid >> 6;
  const int l31 = lane & 31, lh = lane >> 5;
  const int bh = blockIdx.x;
  const int q0 = blockIdx.y * QBLK + w * 64;
  const size_t base = (size_t)bh * (size_t)(SEQ * HD);

  // Q fragments (B-operand): col q = l31, k = d = ds*16 + lh*8 + i
  f16x8 qf[2][4];
  #pragma unroll
  for (int qt = 0; qt < 2; qt++)
    #pragma unroll
    for (int ds = 0; ds < 4; ds++)
      qf[qt][ds] = *(const f16x8*)(Qd + base + (size_t)(q0 + qt * 32 + l31) * HD +
                                   ds * 16 + lh * 8);

  f32x16 o[2][2] = {};          // [qt][hdt]
  float lsum0 = 0.f, lsum1 = 0.f;

#define STAGE(kvt, buf) do {                                                \
    const short* ks_ = KB + base + (size_t)(kvt) * 4096;                    \
    const short* vs_ = VB + base + (size_t)(kvt) * 4096;                    \
    async_load16(ks_ + tid * 8, &Kl[buf][tid * 8]);                         \
    async_load16(ks_ + (tid + 256) * 8, &Kl[buf][(tid + 256) * 8]);         \
    async_load16(vs_ + tid * 8, &Vl[buf][tid * 8]);                         \
    async_load16(vs_ + (tid + 256) * 8, &Vl[buf][(tid + 256) * 8]);         \
  } while (0)

  auto compute = [&](int cur) {
    f16x8 p0[4], p1[4];           // [qt][ks] PV A-fragments
    {
      f16x8 kf[4];
      #pragma unroll
      for (int ds = 0; ds < 4; ds++)
        kf[ds] = *(const f16x8*)&Kl[cur][(ds * 64 + lane) * 8];
      f32x16 sA0 = {}, sA1 = {};
      #pragma unroll
      for (int ds = 0; ds < 4; ds++) {
        sA0 = __builtin_amdgcn_mfma_f32_32x32x16_f16(kf[ds], qf[0][ds], sA0, 0, 0, 0);
        sA1 = __builtin_amdgcn_mfma_f32_32x32x16_f16(kf[ds], qf[1][ds], sA1, 0, 0, 0);
      }
      PACK8(sA0, 0, lsum0, p0[0]); PACK8(sA0, 8, lsum0, p0[1]);
      PACK8(sA1, 0, lsum1, p1[0]); PACK8(sA1, 8, lsum1, p1[1]);
    }
    {
      f16x8 kf[4];
      #pragma unroll
      for (int ds = 0; ds < 4; ds++)
        kf[ds] = *(const f16x8*)&Kl[cur][((4 + ds) * 64 + lane) * 8];
      f32x16 sB0 = {}, sB1 = {};
      #pragma unroll
      for (int ds = 0; ds < 4; ds++) {
        sB0 = __builtin_amdgcn_mfma_f32_32x32x16_f16(kf[ds], qf[0][ds], sB0, 0, 0, 0);
        sB1 = __builtin_amdgcn_mfma_f32_32x32x16_f16(kf[ds], qf[1][ds], sB1, 0, 0, 0);
      }
      PACK8(sB0, 0, lsum0, p0[2]); PACK8(sB0, 8, lsum0, p0[3]);
      PACK8(sB1, 0, lsum1, p1[2]); PACK8(sB1, 8, lsum1, p1[3]);
    }
    f16x8 vf[4][2];
    #pragma unroll
    for (int ks = 0; ks < 4; ks++)
      #pragma unroll
      for (int hdt = 0; hdt < 2; hdt++)
        vf[ks][hdt] = *(const f16x8*)&Vl[cur][((ks * 2 + hdt) * 64 + lane) * 8];
    #pragma unroll
    for (int ks = 0; ks < 4; ks++) {
      o[0][0] = __builtin_amdgcn_mfma_f32_32x32x16_f16(p0[ks], vf[ks][0], o[0][0], 0, 0, 0);
      o[0][1] = __builtin_amdgcn_mfma_f32_32x32x16_f16(p0[ks], vf[ks][1], o[0][1], 0, 0, 0);
      o[1][0] = __builtin_amdgcn_mfma_f32_32x32x16_f16(p1[ks], vf[ks][0], o[1][0], 0, 0, 0);
      o[1][1] = __builtin_amdgcn_mfma_f32_32x32x16_f16(p1[ks], vf[ks][1], o[1][1], 0, 0, 0);
    }
  };

  STAGE(0, 0);
  __syncthreads();
  for (int kvt = 0; kvt < NKVT; kvt++) {
    int cur = kvt & 1;
    if (kvt + 1 < NKVT) STAGE(kvt + 1, cur ^ 1);
    compute(cur);
    __syncthreads();
  }
#undef STAGE

  // softmax denominators: lanes l and l^32 hold complementary kv's of q=l31
  lsum0 += __shfl_xor(lsum0, 32);
  lsum1 += __shfl_xor(lsum1, 32);
  float inv0 = 1.f / lsum0, inv1 = 1.f / lsum1;

  const int b = bh >> 4, h = bh & 15;
  #pragma unroll
  for (int reg = 0; reg < 16; reg++) {
    int qrow = (reg & 3) + 8 * (reg >> 2) + 4 * lh;
    float s0 = __shfl(inv0, qrow);    // inv for q-col qrow lives in lane qrow
    float s1 = __shfl(inv1, qrow);
    size_t r0 = (size_t)(b * SEQ + q0 + qrow) * DIM + h * 64;
    size_t r1 = (size_t)(b * SEQ + q0 + 32 + qrow) * DIM + h * 64;
    Od[r0 + l31]      = f2h(o[0][0][reg] * s0);
    Od[r0 + 32 + l31] = f2h(o[0][1][reg] * s0);
    Od[r1 + l31]      = f2h(o[1][0][reg] * s1);
    Od[r1 + 32 + l31] = f2h(o[1][1][reg] * s1);
  }
}

extern "C" void kernel_launch(void* const* d_in, const int* in_sizes, int n_in,
                              void* d_out, int out_size, void* d_ws, size_t ws_size,
                              hipStream_t stream) {
  const float* x     = (const float*)d_in[0];
  const float* Wqkv  = (const float*)d_in[1];
  const float* bqkv  = (const float*)d_in[2];
  const float* Wproj = (const float*)d_in[3];
  const float* bproj = (const float*)d_in[4];
  float* out = (float*)d_out;

  char* ws = (char*)d_ws;                       // needs 48 MB
  short* x_h    = (short*)(ws);                 //  8 MB  x as f16
  short* Wqkv_t = (short*)(ws + ((size_t)8  << 20));  // 6 MB
  short* Wproj_t= (short*)(ws + ((size_t)14 << 20));  // 2 MB
  short* Qd     = (short*)(ws + ((size_t)16 << 20));  // 8 MB (bh, n, hd)
  short* Kd     = (short*)(ws + ((size_t)24 << 20));  // 8 MB K fragment-major
  short* Vtd    = (short*)(ws + ((size_t)32 << 20));  // 8 MB V fragment-major
  short* Od     = (short*)(ws + ((size_t)40 << 20));  // 8 MB

  // 1. x -> f16
  k_cvt<<<(MROWS * DIM / 4 + 255) / 256, 256, 0, stream>>>(x, x_h, MROWS * DIM / 4);
  // 2. weights -> transposed f16 (N x K)
  dim3 tb(32, 8);
  k_transpose<<<dim3(3 * DIM / 32, DIM / 32), tb, 0, stream>>>(Wqkv, Wqkv_t, DIM, 3 * DIM);
  k_transpose<<<dim3(DIM / 32, DIM / 32), tb, 0, stream>>>(Wproj, Wproj_t, DIM, DIM);
  // 3. QKV GEMM + split/fragment epilogue
  k_gemm_bt<0><<<dim3(3 * DIM / 128, MROWS / 128), 256, 0, stream>>>(
      x_h, Wqkv_t, bqkv, Qd, Kd, Vtd, nullptr, 3 * DIM, DIM);
  // 4. flash attention
  k_flash<<<dim3(BATCH * NH, SEQ / QBLK), 256, 0, stream>>>(Qd, Kd, Vtd, Od);
  // 5. proj GEMM -> f32 out
  k_gemm_bt<1><<<dim3(DIM / 128, MROWS / 128), 256, 0, stream>>>(
      Od, Wproj_t, bproj, nullptr, nullptr, nullptr, out, DIM, DIM);
}

// Round 8
// 153.798 us; speedup vs baseline: 1.0528x; 1.0528x over previous
//
#include <hip/hip_runtime.h>
#include <stdint.h>

#define BATCH 2
#define NH 16
#define SEQ 2048
#define DIM 1024
#define HD 64
#define MROWS (BATCH*SEQ)   // 4096

typedef __attribute__((ext_vector_type(8))) _Float16 f16x8;
typedef __attribute__((ext_vector_type(16))) float f32x16;
typedef __attribute__((ext_vector_type(4))) float f32x4;
typedef __attribute__((ext_vector_type(2))) __fp16 fp16x2;
typedef __attribute__((ext_vector_type(4))) short short4v;

__device__ __forceinline__ short f2h(float f) {
  union { _Float16 h; short s; } u;
  u.h = (_Float16)f;
  return u.s;
}

__device__ __forceinline__ float fast_exp2(float x) {
#if __has_builtin(__builtin_amdgcn_exp2f)
  return __builtin_amdgcn_exp2f(x);
#else
  return exp2f(x);
#endif
}

__device__ __forceinline__ unsigned pk2(float a, float b) {
  union { fp16x2 h; unsigned u; } x;
  x.h = __builtin_amdgcn_cvt_pkrtz(a, b);
  return x.u;
}

// a.hi(lanes32-63) <-> b.lo(lanes0-31), via known-good shuffle primitives.
__device__ __forceinline__ void perm32swap(unsigned &a, unsigned &b) {
  unsigned as = (unsigned)__shfl_xor((int)a, 32);
  unsigned bs = (unsigned)__shfl_xor((int)b, 32);
  bool lo = ((threadIdx.x & 63) < 32);
  unsigned na = lo ? a : bs;   // hi lanes receive b.lo
  unsigned nb = lo ? as : b;   // lo lanes receive a.hi
  a = na; b = nb;
}

__device__ __forceinline__ void async_load16(const void* g, void* l) {
  __builtin_amdgcn_global_load_lds((const __attribute__((address_space(1))) void*)g,
                                   (__attribute__((address_space(3))) void*)l, 16, 0, 0);
}

// ---------------- convert f32 -> f16 ----------------
__global__ __launch_bounds__(256) void k_cvt(const float* __restrict__ in,
                                             short* __restrict__ out, int n4) {
  int i = blockIdx.x * 256 + threadIdx.x;
  if (i >= n4) return;
  float4 v = ((const float4*)in)[i];
  short4v o;
  o[0] = f2h(v.x); o[1] = f2h(v.y); o[2] = f2h(v.z); o[3] = f2h(v.w);
  ((short4v*)out)[i] = o;
}

// ---------------- transpose (K x N) f32 -> (N x K) f16 ----------------
__global__ __launch_bounds__(256) void k_transpose(const float* __restrict__ in,
                                                   short* __restrict__ out,
                                                   int K, int N) {
  __shared__ float t[32][33];
  int n0 = blockIdx.x * 32, k0 = blockIdx.y * 32;
  int tx = threadIdx.x, ty = threadIdx.y;  // 32 x 8
  #pragma unroll
  for (int i = 0; i < 32; i += 8)
    t[ty + i][tx] = in[(size_t)(k0 + ty + i) * N + (n0 + tx)];
  __syncthreads();
  #pragma unroll
  for (int i = 0; i < 32; i += 8)
    out[(size_t)(n0 + ty + i) * K + (k0 + tx)] = f2h(t[tx][ty + i]);
}

// ---------------- GEMM  C[M,N] = A[M,K] * Bt[N,K]^T  (fp16 in, f32 acc) ---
// MODE 0: QKV epilogue -> Q (n-major, scaled by scale*log2e),
//         K,V in MFMA-fragment-major layouts for k_flash (see k_flash docs)
// MODE 1: f32 output + bias
template <int MODE>
__global__ __launch_bounds__(256) void k_gemm_bt(
    const short* __restrict__ A, const short* __restrict__ Bt,
    const float* __restrict__ bias,
    short* __restrict__ Qd, short* __restrict__ Kd, short* __restrict__ Vtd,
    float* __restrict__ Cf, int Ncols, int Kdim) {
  constexpr int BM = 128, BN = 128, BK = 32;
  __shared__ short Al[BM * BK];
  __shared__ short Bl[BN * BK];
  const int tid = threadIdx.x;
  const int lane = tid & 63;
  const int wid = tid >> 6;
  const int wr = wid >> 1, wc = wid & 1;
  const int m0 = blockIdx.y * BM, n0 = blockIdx.x * BN;
  const int l15 = lane & 15, lk = (lane >> 4) * 8;

  f32x4 acc[4][4] = {};

  for (int k0 = 0; k0 < Kdim; k0 += BK) {
    __syncthreads();
    #pragma unroll
    for (int i = 0; i < 2; i++) {
      int c = i * 256 + tid;                 // 512 chunks of 16B = 8KB tile
      async_load16(A + (size_t)(m0 + (c >> 2)) * Kdim + k0 + (c & 3) * 8, &Al[c * 8]);
    }
    #pragma unroll
    for (int i = 0; i < 2; i++) {
      int c = i * 256 + tid;
      async_load16(Bt + (size_t)(n0 + (c >> 2)) * Kdim + k0 + (c & 3) * 8, &Bl[c * 8]);
    }
    __syncthreads();  // compiler emits vmcnt(0) drain before barrier

    f16x8 af[4], bfr[4];
    #pragma unroll
    for (int i = 0; i < 4; i++)
      af[i] = *(const f16x8*)&Al[(wr * 64 + i * 16 + l15) * BK + lk];
    #pragma unroll
    for (int j = 0; j < 4; j++)
      bfr[j] = *(const f16x8*)&Bl[(wc * 64 + j * 16 + l15) * BK + lk];
    #pragma unroll
    for (int i = 0; i < 4; i++)
      #pragma unroll
      for (int j = 0; j < 4; j++)
        acc[i][j] = __builtin_amdgcn_mfma_f32_16x16x32_f16(af[i], bfr[j], acc[i][j], 0, 0, 0);
  }

  const int rl = (lane >> 4) * 4;
  if (MODE == 0) {
    #pragma unroll
    for (int j = 0; j < 4; j++) {
      int col = n0 + wc * 64 + j * 16 + l15;
      float bv = bias[col];
      int sec = col >> 10;          // 0=Q 1=K 2=V
      int cc = col & 1023;
      int h = cc >> 6, hd = cc & 63;
      // fold softmax scale AND log2(e) into Q so attention uses raw exp2
      float mul = (sec == 0) ? (0.125f * 1.44269504088896f) : 1.0f;
      #pragma unroll
      for (int i = 0; i < 4; i++) {
        int rowb = m0 + wr * 64 + i * 16 + rl;
        #pragma unroll
        for (int r = 0; r < 4; r++) {
          int row = rowb + r;
          int b = row >> 11, nr = row & 2047;
          short v = f2h((acc[i][j][r] + bv) * mul);
          size_t bh = (size_t)(b * NH + h);
          size_t base2 = bh * (size_t)(SEQ * HD);
          if (sec == 0) {
            Qd[base2 + (size_t)nr * HD + hd] = v;
          } else if (sec == 1) {
            // K A-frag layout: [(nr>>5)*4 + hd>>4][lane=((hd>>3)&1)*32+(nr&31)][i=hd&7]
            Kd[base2 + (size_t)(((nr >> 5) * 4 + (hd >> 4)) * 512 +
                                (((hd >> 3) & 1) * 32 + (nr & 31)) * 8 + (hd & 7))] = v;
          } else {
            // V B-frag layout: [(nr>>4)*2 + hd>>5][lane=((nr>>3)&1)*32+(hd&31)][i=nr&7]
            Vtd[base2 + (size_t)(((nr >> 4) * 2 + (hd >> 5)) * 512 +
                                 (((nr >> 3) & 1) * 32 + (hd & 31)) * 8 + (nr & 7))] = v;
          }
        }
      }
    }
  } else {
    #pragma unroll
    for (int j = 0; j < 4; j++) {
      int col = n0 + wc * 64 + j * 16 + l15;
      float bv = bias[col];
      #pragma unroll
      for (int i = 0; i < 4; i++) {
        int rowb = m0 + wr * 64 + i * 16 + rl;
        #pragma unroll
        for (int r = 0; r < 4; r++)
          Cf[(size_t)(rowb + r) * Ncols + col] = acc[i][j][r] + bv;
      }
    }
  }
}

// ---------------- flash attention v4 ----------------
// 32x32x16 MFMA, static softmax, P in registers (cvt_pkrtz + shuffle swap).
// Wave owns ONE 32-row q-tile; block = 4 waves = 128 q; grid (32 bh, 16 qb)
// = 512 blocks = 2 blocks/CU (occupancy fix vs v3's 1 block/CU).
// Counted-vmcnt double buffer: raw s_barrier + s_waitcnt vmcnt(4) keeps the
// next tile's 4 staging loads in flight across the barrier (T4).
#define QBLK 128
#define NKVT (SEQ / 64)

// exp2 + pack 8 score regs (R0..R0+7) of one 32x32 C-tile into one PV
// A-fragment (f16x8) for its 16-kv slice.
#define PACK8(sv, R0, lsv, OUT) do {                                        \
    float e0_ = fast_exp2((sv)[R0 + 0]), e1_ = fast_exp2((sv)[R0 + 1]);     \
    float e2_ = fast_exp2((sv)[R0 + 2]), e3_ = fast_exp2((sv)[R0 + 3]);     \
    float e4_ = fast_exp2((sv)[R0 + 4]), e5_ = fast_exp2((sv)[R0 + 5]);     \
    float e6_ = fast_exp2((sv)[R0 + 6]), e7_ = fast_exp2((sv)[R0 + 7]);     \
    lsv += ((e0_ + e1_) + (e2_ + e3_)) + ((e4_ + e5_) + (e6_ + e7_));       \
    unsigned u0_ = pk2(e0_, e1_), u1_ = pk2(e2_, e3_);                      \
    unsigned u2_ = pk2(e4_, e5_), u3_ = pk2(e6_, e7_);                      \
    perm32swap(u0_, u2_);                                                   \
    perm32swap(u1_, u3_);                                                   \
    union { unsigned u[4]; f16x8 v; } W_;                                   \
    W_.u[0] = u0_; W_.u[1] = u1_; W_.u[2] = u2_; W_.u[3] = u3_;             \
    OUT = W_.v;                                                             \
  } while (0)

__global__ __launch_bounds__(256) void k_flash(const short* __restrict__ Qd,
                                               const short* __restrict__ KB,
                                               const short* __restrict__ VB,
                                               short* __restrict__ Od) {
  __shared__ short Kl[2][4096];
  __shared__ short Vl[2][4096];
  const int tid = threadIdx.x;
  const int lane = tid & 63;
  const int w = tid >> 6;
  const int l31 = lane & 31, lh = lane >> 5;
  const int bh = blockIdx.x;
  const int q0 = blockIdx.y * QBLK + w * 32;
  const size_t base = (size_t)bh * (size_t)(SEQ * HD);

  // Q fragments (B-operand): col q = l31, k = d = ds*16 + lh*8 + i
  f16x8 qf[4];
  #pragma unroll
  for (int ds = 0; ds < 4; ds++)
    qf[ds] = *(const f16x8*)(Qd + base + (size_t)(q0 + l31) * HD + ds * 16 + lh * 8);

  f32x16 o[2] = {};          // [hdt]
  float lsum = 0.f;

#define STAGE(kvt, buf) do {                                                \
    const short* ks_ = KB + base + (size_t)(kvt) * 4096;                    \
    const short* vs_ = VB + base + (size_t)(kvt) * 4096;                    \
    async_load16(ks_ + tid * 8, &Kl[buf][tid * 8]);                         \
    async_load16(ks_ + (tid + 256) * 8, &Kl[buf][(tid + 256) * 8]);         \
    async_load16(vs_ + tid * 8, &Vl[buf][tid * 8]);                         \
    async_load16(vs_ + (tid + 256) * 8, &Vl[buf][(tid + 256) * 8]);         \
  } while (0)

  auto compute = [&](int cur) {
    f16x8 kf0[4], kf1[4];
    #pragma unroll
    for (int ds = 0; ds < 4; ds++) {
      kf0[ds] = *(const f16x8*)&Kl[cur][(ds * 64 + lane) * 8];
      kf1[ds] = *(const f16x8*)&Kl[cur][((4 + ds) * 64 + lane) * 8];
    }
    f32x16 sA = {}, sB = {};   // kv 0-31 / kv 32-63 for this wave's 32 q
    __builtin_amdgcn_s_setprio(1);
    #pragma unroll
    for (int ds = 0; ds < 4; ds++) {
      sA = __builtin_amdgcn_mfma_f32_32x32x16_f16(kf0[ds], qf[ds], sA, 0, 0, 0);
      sB = __builtin_amdgcn_mfma_f32_32x32x16_f16(kf1[ds], qf[ds], sB, 0, 0, 0);
    }
    __builtin_amdgcn_s_setprio(0);
    // V reads issued so they land during softmax VALU work
    f16x8 vf[4][2];
    #pragma unroll
    for (int ks = 0; ks < 4; ks++)
      #pragma unroll
      for (int hdt = 0; hdt < 2; hdt++)
        vf[ks][hdt] = *(const f16x8*)&Vl[cur][((ks * 2 + hdt) * 64 + lane) * 8];
    f16x8 p[4];                // PV A-fragments, ks = kv-slice
    PACK8(sA, 0, lsum, p[0]); PACK8(sA, 8, lsum, p[1]);
    PACK8(sB, 0, lsum, p[2]); PACK8(sB, 8, lsum, p[3]);
    __builtin_amdgcn_s_setprio(1);
    #pragma unroll
    for (int ks = 0; ks < 4; ks++) {
      o[0] = __builtin_amdgcn_mfma_f32_32x32x16_f16(p[ks], vf[ks][0], o[0], 0, 0, 0);
      o[1] = __builtin_amdgcn_mfma_f32_32x32x16_f16(p[ks], vf[ks][1], o[1], 0, 0, 0);
    }
    __builtin_amdgcn_s_setprio(0);
  };

  STAGE(0, 0);
  for (int kvt = 0; kvt < NKVT; kvt++) {
    int cur = kvt & 1;
    if (kvt + 1 < NKVT) {
      STAGE(kvt + 1, cur ^ 1);
      asm volatile("s_waitcnt vmcnt(4)" ::: "memory");  // own tile-kvt loads done
    } else {
      asm volatile("s_waitcnt vmcnt(0)" ::: "memory");
    }
    __builtin_amdgcn_s_barrier();          // all waves' staging of buf[cur] landed
    __builtin_amdgcn_sched_barrier(0);     // pin: no ds_read hoists above
    compute(cur);
    __builtin_amdgcn_sched_barrier(0);     // pin: no ds_read sinks below
    __builtin_amdgcn_s_barrier();          // all done reading buf[cur]
  }
#undef STAGE

  // softmax denominators: lanes l and l^32 hold complementary kv's of q=l31
  lsum += __shfl_xor(lsum, 32);
  float inv = 1.f / lsum;

  const int b = bh >> 4, h = bh & 15;
  #pragma unroll
  for (int reg = 0; reg < 16; reg++) {
    int qrow = (reg & 3) + 8 * (reg >> 2) + 4 * lh;
    float s = __shfl(inv, qrow);    // inv for q-col qrow lives in lane qrow
    size_t r0 = (size_t)(b * SEQ + q0 + qrow) * DIM + h * 64;
    Od[r0 + l31]      = f2h(o[0][reg] * s);
    Od[r0 + 32 + l31] = f2h(o[1][reg] * s);
  }
}

extern "C" void kernel_launch(void* const* d_in, const int* in_sizes, int n_in,
                              void* d_out, int out_size, void* d_ws, size_t ws_size,
                              hipStream_t stream) {
  const float* x     = (const float*)d_in[0];
  const float* Wqkv  = (const float*)d_in[1];
  const float* bqkv  = (const float*)d_in[2];
  const float* Wproj = (const float*)d_in[3];
  const float* bproj = (const float*)d_in[4];
  float* out = (float*)d_out;

  char* ws = (char*)d_ws;                       // needs 48 MB
  short* x_h    = (short*)(ws);                 //  8 MB  x as f16
  short* Wqkv_t = (short*)(ws + ((size_t)8  << 20));  // 6 MB
  short* Wproj_t= (short*)(ws + ((size_t)14 << 20));  // 2 MB
  short* Qd     = (short*)(ws + ((size_t)16 << 20));  // 8 MB (bh, n, hd)
  short* Kd     = (short*)(ws + ((size_t)24 << 20));  // 8 MB K fragment-major
  short* Vtd    = (short*)(ws + ((size_t)32 << 20));  // 8 MB V fragment-major
  short* Od     = (short*)(ws + ((size_t)40 << 20));  // 8 MB

  // 1. x -> f16
  k_cvt<<<(MROWS * DIM / 4 + 255) / 256, 256, 0, stream>>>(x, x_h, MROWS * DIM / 4);
  // 2. weights -> transposed f16 (N x K)
  dim3 tb(32, 8);
  k_transpose<<<dim3(3 * DIM / 32, DIM / 32), tb, 0, stream>>>(Wqkv, Wqkv_t, DIM, 3 * DIM);
  k_transpose<<<dim3(DIM / 32, DIM / 32), tb, 0, stream>>>(Wproj, Wproj_t, DIM, DIM);
  // 3. QKV GEMM + split/fragment epilogue
  k_gemm_bt<0><<<dim3(3 * DIM / 128, MROWS / 128), 256, 0, stream>>>(
      x_h, Wqkv_t, bqkv, Qd, Kd, Vtd, nullptr, 3 * DIM, DIM);
  // 4. flash attention
  k_flash<<<dim3(BATCH * NH, SEQ / QBLK), 256, 0, stream>>>(Qd, Kd, Vtd, Od);
  // 5. proj GEMM -> f32 out
  k_gemm_bt<1><<<dim3(DIM / 128, MROWS / 128), 256, 0, stream>>>(
      Od, Wproj_t, bproj, nullptr, nullptr, nullptr, out, DIM, DIM);
}

// Round 9
// 133.664 us; speedup vs baseline: 1.2114x; 1.1506x over previous
//
#include <hip/hip_runtime.h>
#include <stdint.h>

#define BATCH 2
#define NH 16
#define SEQ 2048
#define DIM 1024
#define HD 64
#define MROWS (BATCH*SEQ)   // 4096

typedef __attribute__((ext_vector_type(8))) _Float16 f16x8;
typedef __attribute__((ext_vector_type(16))) float f32x16;
typedef __attribute__((ext_vector_type(4))) float f32x4;
typedef __attribute__((ext_vector_type(2))) __fp16 fp16x2;
typedef __attribute__((ext_vector_type(4))) short short4v;

__device__ __forceinline__ short f2h(float f) {
  union { _Float16 h; short s; } u;
  u.h = (_Float16)f;
  return u.s;
}

__device__ __forceinline__ float fast_exp2(float x) {
#if __has_builtin(__builtin_amdgcn_exp2f)
  return __builtin_amdgcn_exp2f(x);
#else
  return exp2f(x);
#endif
}

__device__ __forceinline__ unsigned pk2(float a, float b) {
  union { fp16x2 h; unsigned u; } x;
  x.h = __builtin_amdgcn_cvt_pkrtz(a, b);
  return x.u;
}

// a.hi(lanes32-63) <-> b.lo(lanes0-31), via known-good shuffle primitives.
__device__ __forceinline__ void perm32swap(unsigned &a, unsigned &b) {
  unsigned as = (unsigned)__shfl_xor((int)a, 32);
  unsigned bs = (unsigned)__shfl_xor((int)b, 32);
  bool lo = ((threadIdx.x & 63) < 32);
  unsigned na = lo ? a : bs;   // hi lanes receive b.lo
  unsigned nb = lo ? as : b;   // lo lanes receive a.hi
  a = na; b = nb;
}

__device__ __forceinline__ void async_load16(const void* g, void* l) {
  __builtin_amdgcn_global_load_lds((const __attribute__((address_space(1))) void*)g,
                                   (__attribute__((address_space(3))) void*)l, 16, 0, 0);
}

// ---------------- convert f32 -> f16 ----------------
__global__ __launch_bounds__(256) void k_cvt(const float* __restrict__ in,
                                             short* __restrict__ out, int n4) {
  int i = blockIdx.x * 256 + threadIdx.x;
  if (i >= n4) return;
  float4 v = ((const float4*)in)[i];
  short4v o;
  o[0] = f2h(v.x); o[1] = f2h(v.y); o[2] = f2h(v.z); o[3] = f2h(v.w);
  ((short4v*)out)[i] = o;
}

// ---------------- transpose (K x N) f32 -> (N x K) f16 ----------------
__global__ __launch_bounds__(256) void k_transpose(const float* __restrict__ in,
                                                   short* __restrict__ out,
                                                   int K, int N) {
  __shared__ float t[32][33];
  int n0 = blockIdx.x * 32, k0 = blockIdx.y * 32;
  int tx = threadIdx.x, ty = threadIdx.y;  // 32 x 8
  #pragma unroll
  for (int i = 0; i < 32; i += 8)
    t[ty + i][tx] = in[(size_t)(k0 + ty + i) * N + (n0 + tx)];
  __syncthreads();
  #pragma unroll
  for (int i = 0; i < 32; i += 8)
    out[(size_t)(n0 + ty + i) * K + (k0 + tx)] = f2h(t[tx][ty + i]);
}

// ---------------- GEMM  C[M,N] = A[M,K] * Bt[N,K]^T  (fp16 in, f32 acc) ---
// BK=64, double-buffered LDS with counted vmcnt (loads in flight across
// barriers), XOR-swizzled LDS (linear global_load_lds dest + inverse-swizzled
// global source + swizzled ds_read — rule #21 pattern).
// MODE 0 (BM=128): QKV epilogue -> Q (scaled scale*log2e), K/V fragment-major
// MODE 1 (BM=64):  f32 output + bias
template <int MODE, int BM>
__global__ __launch_bounds__(256) void k_gemm_bt(
    const short* __restrict__ A, const short* __restrict__ Bt,
    const float* __restrict__ bias,
    short* __restrict__ Qd, short* __restrict__ Kd, short* __restrict__ Vtd,
    float* __restrict__ Cf, int Ncols, int Kdim) {
  constexpr int BN = 128, BK = 64;
  constexpr int RI = BM / 32;            // row fragments per wave
  __shared__ short Al[2][BM * BK];
  __shared__ short Bl[2][BN * BK];
  const int tid = threadIdx.x;
  const int lane = tid & 63;
  const int wid = tid >> 6;
  const int wr = wid >> 1, wc = wid & 1;
  const int m0 = blockIdx.y * BM, n0 = blockIdx.x * BN;
  const int l15 = lane & 15, lk = (lane >> 4) * 8;

  f32x4 acc[RI][4] = {};

  // stage tile kt into buf: LDS dest linear, global col pre-inverse-swizzled
  auto stage = [&](int kt, int buf) {
    int k0 = kt * BK;
    #pragma unroll
    for (int i2 = 0; i2 < BM / 32; i2++) {
      int c = i2 * 256 + tid;
      int r = c >> 3, cs = (c & 7) * 8;
      async_load16(A + (size_t)(m0 + r) * Kdim + k0 + (cs ^ ((r & 7) * 8)),
                   &Al[buf][c * 8]);
    }
    #pragma unroll
    for (int i2 = 0; i2 < 4; i2++) {
      int c = i2 * 256 + tid;
      int r = c >> 3, cs = (c & 7) * 8;
      async_load16(Bt + (size_t)(n0 + r) * Kdim + k0 + (cs ^ ((r & 7) * 8)),
                   &Bl[buf][c * 8]);
    }
  };

  auto compute = [&](int buf) {
    f16x8 af[2][RI], bfr[2][4];
    #pragma unroll
    for (int kk = 0; kk < 2; kk++) {
      #pragma unroll
      for (int i = 0; i < RI; i++) {
        int row = wr * (BM / 2) + i * 16 + l15;
        af[kk][i] = *(const f16x8*)&Al[buf][row * 64 + ((kk * 32 + lk) ^ ((row & 7) * 8))];
      }
      #pragma unroll
      for (int j = 0; j < 4; j++) {
        int row = wc * 64 + j * 16 + l15;
        bfr[kk][j] = *(const f16x8*)&Bl[buf][row * 64 + ((kk * 32 + lk) ^ ((row & 7) * 8))];
      }
    }
    __builtin_amdgcn_s_setprio(1);
    #pragma unroll
    for (int i = 0; i < RI; i++)
      #pragma unroll
      for (int j = 0; j < 4; j++) {
        acc[i][j] = __builtin_amdgcn_mfma_f32_16x16x32_f16(af[0][i], bfr[0][j], acc[i][j], 0, 0, 0);
        acc[i][j] = __builtin_amdgcn_mfma_f32_16x16x32_f16(af[1][i], bfr[1][j], acc[i][j], 0, 0, 0);
      }
    __builtin_amdgcn_s_setprio(0);
  };

  stage(0, 0);
  const int NT = Kdim / BK;
  for (int t = 0; t < NT; t++) {
    int cur = t & 1;
    if (t + 1 < NT) {
      stage(t + 1, cur ^ 1);
      // wait for own tile's loads only; next tile's stay in flight
      if constexpr (BM == 128) asm volatile("s_waitcnt vmcnt(8)" ::: "memory");
      else                     asm volatile("s_waitcnt vmcnt(6)" ::: "memory");
    } else {
      asm volatile("s_waitcnt vmcnt(0)" ::: "memory");
    }
    __builtin_amdgcn_s_barrier();
    __builtin_amdgcn_sched_barrier(0);
    compute(cur);
    __builtin_amdgcn_sched_barrier(0);
    __builtin_amdgcn_s_barrier();
  }

  const int rl = (lane >> 4) * 4;
  if (MODE == 0) {
    #pragma unroll
    for (int j = 0; j < 4; j++) {
      int col = n0 + wc * 64 + j * 16 + l15;
      float bv = bias[col];
      int sec = col >> 10;          // 0=Q 1=K 2=V
      int cc = col & 1023;
      int h = cc >> 6, hd = cc & 63;
      // fold softmax scale AND log2(e) into Q so attention uses raw exp2
      float mul = (sec == 0) ? (0.125f * 1.44269504088896f) : 1.0f;
      #pragma unroll
      for (int i = 0; i < RI; i++) {
        int rowb = m0 + wr * (BM / 2) + i * 16 + rl;
        #pragma unroll
        for (int r = 0; r < 4; r++) {
          int row = rowb + r;
          int b = row >> 11, nr = row & 2047;
          short v = f2h((acc[i][j][r] + bv) * mul);
          size_t bh = (size_t)(b * NH + h);
          size_t base2 = bh * (size_t)(SEQ * HD);
          if (sec == 0) {
            Qd[base2 + (size_t)nr * HD + hd] = v;
          } else if (sec == 1) {
            // K A-frag layout: [(nr>>5)*4 + hd>>4][lane=((hd>>3)&1)*32+(nr&31)][i=hd&7]
            Kd[base2 + (size_t)(((nr >> 5) * 4 + (hd >> 4)) * 512 +
                                (((hd >> 3) & 1) * 32 + (nr & 31)) * 8 + (hd & 7))] = v;
          } else {
            // V B-frag layout: [(nr>>4)*2 + hd>>5][lane=((nr>>3)&1)*32+(hd&31)][i=nr&7]
            Vtd[base2 + (size_t)(((nr >> 4) * 2 + (hd >> 5)) * 512 +
                                 (((nr >> 3) & 1) * 32 + (hd & 31)) * 8 + (nr & 7))] = v;
          }
        }
      }
    }
  } else {
    #pragma unroll
    for (int j = 0; j < 4; j++) {
      int col = n0 + wc * 64 + j * 16 + l15;
      float bv = bias[col];
      #pragma unroll
      for (int i = 0; i < RI; i++) {
        int rowb = m0 + wr * (BM / 2) + i * 16 + rl;
        #pragma unroll
        for (int r = 0; r < 4; r++)
          Cf[(size_t)(rowb + r) * Ncols + col] = acc[i][j][r] + bv;
      }
    }
  }
}

// ---------------- flash attention v4 ----------------
// 32x32x16 MFMA, static softmax, P in registers (cvt_pkrtz + shuffle swap).
// Wave owns ONE 32-row q-tile; block = 4 waves = 128 q; grid (32 bh, 16 qb)
// = 512 blocks = 2 blocks/CU. Counted-vmcnt double buffer.
#define QBLK 128
#define NKVT (SEQ / 64)

// exp2 + pack 8 score regs (R0..R0+7) of one 32x32 C-tile into one PV
// A-fragment (f16x8) for its 16-kv slice.
#define PACK8(sv, R0, lsv, OUT) do {                                        \
    float e0_ = fast_exp2((sv)[R0 + 0]), e1_ = fast_exp2((sv)[R0 + 1]);     \
    float e2_ = fast_exp2((sv)[R0 + 2]), e3_ = fast_exp2((sv)[R0 + 3]);     \
    float e4_ = fast_exp2((sv)[R0 + 4]), e5_ = fast_exp2((sv)[R0 + 5]);     \
    float e6_ = fast_exp2((sv)[R0 + 6]), e7_ = fast_exp2((sv)[R0 + 7]);     \
    lsv += ((e0_ + e1_) + (e2_ + e3_)) + ((e4_ + e5_) + (e6_ + e7_));       \
    unsigned u0_ = pk2(e0_, e1_), u1_ = pk2(e2_, e3_);                      \
    unsigned u2_ = pk2(e4_, e5_), u3_ = pk2(e6_, e7_);                      \
    perm32swap(u0_, u2_);                                                   \
    perm32swap(u1_, u3_);                                                   \
    union { unsigned u[4]; f16x8 v; } W_;                                   \
    W_.u[0] = u0_; W_.u[1] = u1_; W_.u[2] = u2_; W_.u[3] = u3_;             \
    OUT = W_.v;                                                             \
  } while (0)

__global__ __launch_bounds__(256) void k_flash(const short* __restrict__ Qd,
                                               const short* __restrict__ KB,
                                               const short* __restrict__ VB,
                                               short* __restrict__ Od) {
  __shared__ short Kl[2][4096];
  __shared__ short Vl[2][4096];
  const int tid = threadIdx.x;
  const int lane = tid & 63;
  const int w = tid >> 6;
  const int l31 = lane & 31, lh = lane >> 5;
  const int bh = blockIdx.x;
  const int q0 = blockIdx.y * QBLK + w * 32;
  const size_t base = (size_t)bh * (size_t)(SEQ * HD);

  // Q fragments (B-operand): col q = l31, k = d = ds*16 + lh*8 + i
  f16x8 qf[4];
  #pragma unroll
  for (int ds = 0; ds < 4; ds++)
    qf[ds] = *(const f16x8*)(Qd + base + (size_t)(q0 + l31) * HD + ds * 16 + lh * 8);

  f32x16 o[2] = {};          // [hdt]
  float lsum = 0.f;

#define STAGE(kvt, buf) do {                                                \
    const short* ks_ = KB + base + (size_t)(kvt) * 4096;                    \
    const short* vs_ = VB + base + (size_t)(kvt) * 4096;                    \
    async_load16(ks_ + tid * 8, &Kl[buf][tid * 8]);                         \
    async_load16(ks_ + (tid + 256) * 8, &Kl[buf][(tid + 256) * 8]);         \
    async_load16(vs_ + tid * 8, &Vl[buf][tid * 8]);                         \
    async_load16(vs_ + (tid + 256) * 8, &Vl[buf][(tid + 256) * 8]);         \
  } while (0)

  auto compute = [&](int cur) {
    f16x8 kf0[4], kf1[4];
    #pragma unroll
    for (int ds = 0; ds < 4; ds++) {
      kf0[ds] = *(const f16x8*)&Kl[cur][(ds * 64 + lane) * 8];
      kf1[ds] = *(const f16x8*)&Kl[cur][((4 + ds) * 64 + lane) * 8];
    }
    f32x16 sA = {}, sB = {};   // kv 0-31 / kv 32-63 for this wave's 32 q
    __builtin_amdgcn_s_setprio(1);
    #pragma unroll
    for (int ds = 0; ds < 4; ds++) {
      sA = __builtin_amdgcn_mfma_f32_32x32x16_f16(kf0[ds], qf[ds], sA, 0, 0, 0);
      sB = __builtin_amdgcn_mfma_f32_32x32x16_f16(kf1[ds], qf[ds], sB, 0, 0, 0);
    }
    __builtin_amdgcn_s_setprio(0);
    // V reads issued so they land during softmax VALU work
    f16x8 vf[4][2];
    #pragma unroll
    for (int ks = 0; ks < 4; ks++)
      #pragma unroll
      for (int hdt = 0; hdt < 2; hdt++)
        vf[ks][hdt] = *(const f16x8*)&Vl[cur][((ks * 2 + hdt) * 64 + lane) * 8];
    f16x8 p[4];                // PV A-fragments, ks = kv-slice
    PACK8(sA, 0, lsum, p[0]); PACK8(sA, 8, lsum, p[1]);
    PACK8(sB, 0, lsum, p[2]); PACK8(sB, 8, lsum, p[3]);
    __builtin_amdgcn_s_setprio(1);
    #pragma unroll
    for (int ks = 0; ks < 4; ks++) {
      o[0] = __builtin_amdgcn_mfma_f32_32x32x16_f16(p[ks], vf[ks][0], o[0], 0, 0, 0);
      o[1] = __builtin_amdgcn_mfma_f32_32x32x16_f16(p[ks], vf[ks][1], o[1], 0, 0, 0);
    }
    __builtin_amdgcn_s_setprio(0);
  };

  STAGE(0, 0);
  for (int kvt = 0; kvt < NKVT; kvt++) {
    int cur = kvt & 1;
    if (kvt + 1 < NKVT) {
      STAGE(kvt + 1, cur ^ 1);
      asm volatile("s_waitcnt vmcnt(4)" ::: "memory");  // own tile-kvt loads done
    } else {
      asm volatile("s_waitcnt vmcnt(0)" ::: "memory");
    }
    __builtin_amdgcn_s_barrier();          // all waves' staging of buf[cur] landed
    __builtin_amdgcn_sched_barrier(0);     // pin: no ds_read hoists above
    compute(cur);
    __builtin_amdgcn_sched_barrier(0);     // pin: no ds_read sinks below
    __builtin_amdgcn_s_barrier();          // all done reading buf[cur]
  }
#undef STAGE

  // softmax denominators: lanes l and l^32 hold complementary kv's of q=l31
  lsum += __shfl_xor(lsum, 32);
  float inv = 1.f / lsum;

  const int b = bh >> 4, h = bh & 15;
  #pragma unroll
  for (int reg = 0; reg < 16; reg++) {
    int qrow = (reg & 3) + 8 * (reg >> 2) + 4 * lh;
    float s = __shfl(inv, qrow);    // inv for q-col qrow lives in lane qrow
    size_t r0 = (size_t)(b * SEQ + q0 + qrow) * DIM + h * 64;
    Od[r0 + l31]      = f2h(o[0][reg] * s);
    Od[r0 + 32 + l31] = f2h(o[1][reg] * s);
  }
}

extern "C" void kernel_launch(void* const* d_in, const int* in_sizes, int n_in,
                              void* d_out, int out_size, void* d_ws, size_t ws_size,
                              hipStream_t stream) {
  const float* x     = (const float*)d_in[0];
  const float* Wqkv  = (const float*)d_in[1];
  const float* bqkv  = (const float*)d_in[2];
  const float* Wproj = (const float*)d_in[3];
  const float* bproj = (const float*)d_in[4];
  float* out = (float*)d_out;

  char* ws = (char*)d_ws;                       // needs 48 MB
  short* x_h    = (short*)(ws);                 //  8 MB  x as f16
  short* Wqkv_t = (short*)(ws + ((size_t)8  << 20));  // 6 MB
  short* Wproj_t= (short*)(ws + ((size_t)14 << 20));  // 2 MB
  short* Qd     = (short*)(ws + ((size_t)16 << 20));  // 8 MB (bh, n, hd)
  short* Kd     = (short*)(ws + ((size_t)24 << 20));  // 8 MB K fragment-major
  short* Vtd    = (short*)(ws + ((size_t)32 << 20));  // 8 MB V fragment-major
  short* Od     = (short*)(ws + ((size_t)40 << 20));  // 8 MB

  // 1. x -> f16
  k_cvt<<<(MROWS * DIM / 4 + 255) / 256, 256, 0, stream>>>(x, x_h, MROWS * DIM / 4);
  // 2. weights -> transposed f16 (N x K)
  dim3 tb(32, 8);
  k_transpose<<<dim3(3 * DIM / 32, DIM / 32), tb, 0, stream>>>(Wqkv, Wqkv_t, DIM, 3 * DIM);
  k_transpose<<<dim3(DIM / 32, DIM / 32), tb, 0, stream>>>(Wproj, Wproj_t, DIM, DIM);
  // 3. QKV GEMM + split/fragment epilogue (BM=128)
  k_gemm_bt<0, 128><<<dim3(3 * DIM / 128, MROWS / 128), 256, 0, stream>>>(
      x_h, Wqkv_t, bqkv, Qd, Kd, Vtd, nullptr, 3 * DIM, DIM);
  // 4. flash attention
  k_flash<<<dim3(BATCH * NH, SEQ / QBLK), 256, 0, stream>>>(Qd, Kd, Vtd, Od);
  // 5. proj GEMM -> f32 out (BM=64: 512 blocks = 2/CU)
  k_gemm_bt<1, 64><<<dim3(DIM / 128, MROWS / 64), 256, 0, stream>>>(
      Od, Wproj_t, bproj, nullptr, nullptr, nullptr, out, DIM, DIM);
}